// Round 1
// baseline (351.600 us; speedup 1.0000x reference)
//
#include <hip/hip_runtime.h>
#include <math.h>

namespace {
constexpr int kFeat = 112;
constexpr int kBatch = 256;
constexpr int kTotal = 96981;          // sum of window counts over 13 ratios
constexpr int kSatStride = 115;        // 113 cols padded to odd stride -> no bank conflicts
constexpr int kRH[13] = {16,12,20,24,20,28,32,24,40,28,40,28,36};
constexpr int kRW[13] = {16,20,12,24,28,20,32,40,24,40,28,36,28};
constexpr int kOff[13] = {0,9409,18802,28195,36116,44021,51926,58487,64984,71481,77686,83891,90436};
}

// One block per image: build 113x113 summed-area table in LDS, then emit all
// 96981 window averages with 4 LDS reads each.
__global__ __launch_bounds__(256) void sat_scores_kernel(const float* __restrict__ x,
                                                         float* __restrict__ win) {
  __shared__ float sat[113 * kSatStride];   // 51,980 B
  const int b = blockIdx.x;
  const int tid = threadIdx.x;
  const float* xb = x + (size_t)b * kFeat * kFeat;

  // zero border row 0 / col 0
  for (int j = tid; j < 113; j += 256) { sat[j] = 0.f; sat[j * kSatStride] = 0.f; }
  // load image into sat[1..112][1..112]
  for (int i = tid; i < kFeat * kFeat; i += 256) {
    const int r = i / kFeat, c = i - r * kFeat;
    sat[(r + 1) * kSatStride + (c + 1)] = xb[i];
  }
  __syncthreads();

  // row prefix sums (one thread per row; odd stride keeps banks spread)
  if (tid < kFeat) {
    float s = 0.f;
    const int row = (tid + 1) * kSatStride;
    for (int c = 1; c <= kFeat; ++c) { s += sat[row + c]; sat[row + c] = s; }
  }
  __syncthreads();

  // column prefix sums (one thread per column; consecutive addresses across lanes)
  if (tid < kFeat) {
    float s = 0.f;
    const int col = tid + 1;
    for (int r = 1; r <= kFeat; ++r) { s += sat[r * kSatStride + col]; sat[r * kSatStride + col] = s; }
  }
  __syncthreads();

  float* wb = win + (size_t)b * kTotal;
#pragma unroll
  for (int rr = 0; rr < 13; ++rr) {
    const int rh = kRH[rr], rw = kRW[rr];
    const int nr = kFeat - rh + 1;
    const int nc = kFeat - rw + 1;   // compile-time per unrolled iteration -> magic-mul division
    const float inv = 1.0f / (float)(rh * rw);
    for (int i = tid; i < nr * nc; i += 256) {
      const int xi = i / nc, yi = i - xi * nc;
      const float s = sat[(xi + rh) * kSatStride + (yi + rw)]
                    - sat[ xi       * kSatStride + (yi + rw)]
                    - sat[(xi + rh) * kSatStride +  yi      ]
                    + sat[ xi       * kSatStride +  yi      ];
      wb[kOff[rr] + i] = s * inv;
    }
  }
}

// One block per (batch, group). Greedy NMS, n_pick<=3: recompute liveness per
// pass against previously picked boxes (conjunctive suppression == reference's
// accumulated keep-mask). Exact reference IoU float arithmetic.
__global__ __launch_bounds__(256) void nms_kernel(const float* __restrict__ coords,
                                                  const float* __restrict__ win,
                                                  float* __restrict__ out_idx,
                                                  float* __restrict__ out_sc) {
  const int bz = blockIdx.x;
  const int b = bz / 3;
  const int g = bz - b * 3;
  const int s0   = (g == 0) ? 0     : (g == 1) ? 28195 : 51926;
  const int gsz  = (g == 0) ? 28195 : (g == 1) ? 23731 : 45055;
  const int np   = (g == 1) ? 3 : 2;
  const int slot = (g == 0) ? 0 : (g == 1) ? 2 : 5;
  const int tid = threadIdx.x;
  const float* sc = win + (size_t)b * kTotal + s0;
  const float* cd = coords + (size_t)s0 * 4;

  __shared__ float rs[256];
  __shared__ int   ri[256];
  __shared__ float pbox[3][4];
  __shared__ float parea[3];
  __shared__ int   pidx[3];

  for (int k = 0; k < np; ++k) {
    float best = -INFINITY;
    int bi = 0x7fffffff;
    for (int i = tid; i < gsz; i += 256) {
      bool alive = true;
      if (k > 0) {
        const float x0 = cd[4 * i + 0], y0 = cd[4 * i + 1];
        const float x1 = cd[4 * i + 2], y1 = cd[4 * i + 3];
        for (int p = 0; p < k; ++p) {
          if (i == pidx[p]) { alive = false; break; }
          const float lx = fmaxf(x0, pbox[p][0]);
          const float ly = fmaxf(y0, pbox[p][1]);
          const float rx = fminf(x1, pbox[p][2]);
          const float ry = fminf(y1, pbox[p][3]);
          const float w = rx - lx + 1.0f;
          const float h = ry - ly + 1.0f;
          const float inter = (w < 0.f || h < 0.f) ? 0.f : w * h;
          const float ai = (x1 - x0 + 1.0f) * (y1 - y0 + 1.0f);
          const float iou = inter / (ai + parea[p] - inter);
          if (iou > 0.25f) { alive = false; break; }
        }
      }
      if (alive) {
        const float s = sc[i];
        if (s > best) { best = s; bi = i; }   // i increasing -> keeps first max in-thread
      }
    }
    rs[tid] = best; ri[tid] = bi;
    __syncthreads();
    for (int off = 128; off > 0; off >>= 1) {
      if (tid < off) {
        const float s2 = rs[tid + off];
        const int   i2 = ri[tid + off];
        if (s2 > rs[tid] || (s2 == rs[tid] && i2 < ri[tid])) { rs[tid] = s2; ri[tid] = i2; }
      }
      __syncthreads();
    }
    if (tid == 0) {
      const int pi = ri[0];
      pidx[k] = pi;
      const float x0 = cd[4 * pi + 0], y0 = cd[4 * pi + 1];
      const float x1 = cd[4 * pi + 2], y1 = cd[4 * pi + 3];
      pbox[k][0] = x0; pbox[k][1] = y0; pbox[k][2] = x1; pbox[k][3] = y1;
      parea[k] = (x1 - x0 + 1.0f) * (y1 - y0 + 1.0f);
      out_idx[b * 7 + slot + k] = (float)(s0 + pi);
      out_sc[b * 7 + slot + k] = rs[0];
    }
    __syncthreads();
  }
}

extern "C" void kernel_launch(void* const* d_in, const int* in_sizes, int n_in,
                              void* d_out, int out_size, void* d_ws, size_t ws_size,
                              hipStream_t stream) {
  const float* x      = (const float*)d_in[0];
  const float* coords = (const float*)d_in[1];
  float* out     = (float*)d_out;
  float* out_idx = out;                      // (256,7) indices as float values
  float* out_sc  = out + kBatch * 7;         // (256,7) picked scores
  float* win     = out + 2 * kBatch * 7;     // (256,96981) window scores

  sat_scores_kernel<<<kBatch, 256, 0, stream>>>(x, win);
  nms_kernel<<<kBatch * 3, 256, 0, stream>>>(coords, win, out_idx, out_sc);
}

// Round 2
// 184.080 us; speedup vs baseline: 1.9100x; 1.9100x over previous
//
#include <hip/hip_runtime.h>
#include <math.h>
#include <limits.h>

namespace {
constexpr int kFeat = 112;
constexpr int kBatch = 256;
constexpr int kTotal = 96981;
constexpr int kStride = 115;          // 113 cols padded; 115%32=19 coprime -> spread banks
constexpr int kNT = 1024;             // 16 waves / block, one block per CU
constexpr int kRH[13] = {16,12,20,24,20,28,32,24,40,28,40,28,36};
constexpr int kRW[13] = {16,20,12,24,28,20,32,40,24,40,28,36,28};
constexpr int kOff[13] = {0,9409,18802,28195,36116,44021,51926,58487,64984,71481,77686,83891,90436};
}

struct NmsShared {
  float rs[kNT / 64];
  int   ri[kNT / 64];
  float shS; int shI;
  float pX0[3], pY0[3], pX1[3], pY1[3], pA[3];
  int   pI[3];
};

__device__ inline void block_argmax(float s, int i, NmsShared* ns) {
  __syncthreads();                       // protect rs/ri reuse across passes
#pragma unroll
  for (int off = 32; off > 0; off >>= 1) {
    const float s2 = __shfl_down(s, off, 64);
    const int   i2 = __shfl_down(i, off, 64);
    if (s2 > s || (s2 == s && i2 < i)) { s = s2; i = i2; }
  }
  const int wave = threadIdx.x >> 6;
  if ((threadIdx.x & 63) == 0) { ns->rs[wave] = s; ns->ri[wave] = i; }
  __syncthreads();
  if (threadIdx.x == 0) {
    float bs = ns->rs[0]; int bi = ns->ri[0];
#pragma unroll
    for (int w = 1; w < kNT / 64; ++w) {
      if (ns->rs[w] > bs || (ns->rs[w] == bs && ns->ri[w] < bi)) { bs = ns->rs[w]; bi = ns->ri[w]; }
    }
    ns->shS = bs; ns->shI = bi;
  }
  __syncthreads();
}

// thread 0: decode global window index -> coords, stash picked box, write outputs
template<int RB, int RE>
__device__ inline void pick_store(NmsShared* ns, int k, int slot,
                                  float* __restrict__ out_idx, float* __restrict__ out_sc, int b) {
  if (threadIdx.x == 0) {
    const int pi = ns->shI;
#pragma unroll
    for (int rr = RB; rr < RE; ++rr) {
      const int nr = kFeat - kRH[rr] + 1, nc = kFeat - kRW[rr] + 1;
      if (pi >= kOff[rr] && pi < kOff[rr] + nr * nc) {
        const int l = pi - kOff[rr];
        const int xi = l / nc, yi = l - xi * nc;
        const float x0u = xi * 4.0f - 1.0f, y0u = yi * 4.0f - 1.0f;
        const float x1 = x0u + kRH[rr] * 4.0f, y1 = y0u + kRW[rr] * 4.0f;
        const float x0 = fmaxf(x0u, 0.0f), y0 = fmaxf(y0u, 0.0f);
        ns->pX0[k] = x0; ns->pY0[k] = y0; ns->pX1[k] = x1; ns->pY1[k] = y1;
        ns->pA[k] = (x1 - x0 + 1.0f) * (y1 - y0 + 1.0f);
        ns->pI[k] = pi;
      }
    }
    out_idx[b * 7 + slot + k] = (float)pi;
    out_sc [b * 7 + slot + k] = ns->shS;
  }
  __syncthreads();
}

template<int RB, int RE, int NP, int SLOT>
__device__ inline void nms_group(const float* __restrict__ sat, NmsShared* ns,
                                 float best0, int bi0,
                                 float* __restrict__ out_idx, float* __restrict__ out_sc, int b) {
  const int tid = threadIdx.x;
  // pass 0: argmax tracked during scoring
  block_argmax(best0, bi0, ns);
  pick_store<RB, RE>(ns, 0, SLOT, out_idx, out_sc, b);
  for (int k = 1; k < NP; ++k) {
    float best = -INFINITY; int bi = INT_MAX;
#pragma unroll
    for (int rr = RB; rr < RE; ++rr) {
      const int rh = kRH[rr], rw = kRW[rr];
      const int nr = kFeat - rh + 1, nc = kFeat - rw + 1;
      const float inv = 1.0f / (float)(rh * rw);
      for (int i = tid; i < nr * nc; i += kNT) {
        const int xi = i / nc, yi = i - xi * nc;     // nc compile-time -> magic mul
        const int gi = kOff[rr] + i;
        const float x0u = xi * 4.0f - 1.0f, y0u = yi * 4.0f - 1.0f;
        const float x1 = x0u + rh * 4.0f, y1 = y0u + rw * 4.0f;
        const float x0 = fmaxf(x0u, 0.0f), y0 = fmaxf(y0u, 0.0f);
        const float a = (x1 - x0 + 1.0f) * (y1 - y0 + 1.0f);
        bool alive = true;
        for (int p = 0; p < k; ++p) {
          if (gi == ns->pI[p]) { alive = false; break; }
          const float lx = fmaxf(x0, ns->pX0[p]), ly = fmaxf(y0, ns->pY0[p]);
          const float rx = fminf(x1, ns->pX1[p]), ry = fminf(y1, ns->pY1[p]);
          const float w = rx - lx + 1.0f, h = ry - ly + 1.0f;
          const float inter = (w < 0.0f || h < 0.0f) ? 0.0f : w * h;
          const float iou = inter / (a + ns->pA[p] - inter);
          if (iou > 0.25f) { alive = false; break; }
        }
        if (alive) {
          const float s = (sat[(xi + rh) * kStride + (yi + rw)]
                         - sat[ xi       * kStride + (yi + rw)]
                         - sat[(xi + rh) * kStride +  yi      ]
                         + sat[ xi       * kStride +  yi      ]) * inv;
          if (s > best) { best = s; bi = gi; }       // ascending gi -> first-max tie-break
        }
      }
    }
    block_argmax(best, bi, ns);
    pick_store<RB, RE>(ns, k, SLOT, out_idx, out_sc, b);
  }
}

__global__ __launch_bounds__(kNT, 4) void appm_fused(const float* __restrict__ x,
                                                     float* __restrict__ win,
                                                     float* __restrict__ out_idx,
                                                     float* __restrict__ out_sc) {
  __shared__ float sat[113 * kStride];   // 51,980 B
  __shared__ NmsShared ns;
  const int b = blockIdx.x;
  const int tid = threadIdx.x;
  const float* xb = x + (size_t)b * kFeat * kFeat;

  // zero border row 0 / col 0
  for (int j = tid; j < 113; j += kNT) { sat[j] = 0.f; sat[j * kStride] = 0.f; }
  // load image into sat[1..112][1..112]
  for (int i = tid; i < kFeat * kFeat; i += kNT) {
    const int r = i / kFeat, c = i - r * kFeat;
    sat[(r + 1) * kStride + (c + 1)] = xb[i];
  }
  __syncthreads();

  // row prefix sums (one thread per row)
  if (tid < kFeat) {
    float s = 0.f;
    const int row = (tid + 1) * kStride;
    for (int c = 1; c <= kFeat; ++c) { s += sat[row + c]; sat[row + c] = s; }
  }
  __syncthreads();

  // column prefix sums (one thread per column)
  if (tid < kFeat) {
    float s = 0.f;
    const int col = tid + 1;
    for (int r = 1; r <= kFeat; ++r) { s += sat[r * kStride + col]; sat[r * kStride + col] = s; }
  }
  __syncthreads();

  // scoring phase: write all window scores + track per-group pass-0 argmax
  float gb[3] = {-INFINITY, -INFINITY, -INFINITY};
  int gbi[3] = {INT_MAX, INT_MAX, INT_MAX};
  float* wb = win + (size_t)b * kTotal;
#pragma unroll
  for (int rr = 0; rr < 13; ++rr) {
    const int g = (rr < 3) ? 0 : (rr < 6) ? 1 : 2;
    const int rh = kRH[rr], rw = kRW[rr];
    const int nr = kFeat - rh + 1, nc = kFeat - rw + 1;
    const float inv = 1.0f / (float)(rh * rw);
    for (int i = tid; i < nr * nc; i += kNT) {
      const int xi = i / nc, yi = i - xi * nc;
      const float s = (sat[(xi + rh) * kStride + (yi + rw)]
                     - sat[ xi       * kStride + (yi + rw)]
                     - sat[(xi + rh) * kStride +  yi      ]
                     + sat[ xi       * kStride +  yi      ]) * inv;
      wb[kOff[rr] + i] = s;
      if (s > gb[g]) { gb[g] = s; gbi[g] = kOff[rr] + i; }
    }
  }
  // block_argmax starts with __syncthreads, so scores in LDS/sat are stable

  nms_group<0, 3, 2, 0>(sat, &ns, gb[0], gbi[0], out_idx, out_sc, b);
  nms_group<3, 6, 3, 2>(sat, &ns, gb[1], gbi[1], out_idx, out_sc, b);
  nms_group<6, 13, 2, 5>(sat, &ns, gb[2], gbi[2], out_idx, out_sc, b);
}

extern "C" void kernel_launch(void* const* d_in, const int* in_sizes, int n_in,
                              void* d_out, int out_size, void* d_ws, size_t ws_size,
                              hipStream_t stream) {
  const float* x = (const float*)d_in[0];
  float* out     = (float*)d_out;
  float* out_idx = out;                      // (256,7) indices as float values
  float* out_sc  = out + kBatch * 7;         // (256,7) picked scores
  float* win     = out + 2 * kBatch * 7;     // (256,96981) window scores

  appm_fused<<<kBatch, kNT, 0, stream>>>(x, win, out_idx, out_sc);
}

// Round 3
// 180.828 us; speedup vs baseline: 1.9444x; 1.0180x over previous
//
#include <hip/hip_runtime.h>
#include <math.h>
#include <limits.h>

namespace {
constexpr int kFeat = 112;
constexpr int kBatch = 256;
constexpr int kTotal = 96981;
constexpr int kStride = 116;      // /4 -> float4-aligned columns (rw%4==0 for all ratios)
constexpr int kNT = 512;          // 8 waves; 3 blocks/CU (LDS-limited: 3*52.6KB < 160KB)
constexpr int kRH[13] = {16,12,20,24,20,28,32,24,40,28,40,28,36};
constexpr int kRW[13] = {16,20,12,24,28,20,32,40,24,40,28,36,28};
constexpr int kOff[13] = {0,9409,18802,28195,36116,44021,51926,58487,64984,71481,77686,83891,90436};
}

struct NmsShared {
  float rs[kNT / 64];
  int   ri[kNT / 64];
  float shS; int shI;
  float pX0[3], pY0[3], pX1[3], pY1[3], pA[3];
  int   pI[3];
};

__device__ __forceinline__ void block_argmax(float s, int i, NmsShared* ns) {
  __syncthreads();                       // protect rs/ri reuse across passes
#pragma unroll
  for (int off = 32; off > 0; off >>= 1) {
    const float s2 = __shfl_down(s, off, 64);
    const int   i2 = __shfl_down(i, off, 64);
    if (s2 > s || (s2 == s && i2 < i)) { s = s2; i = i2; }
  }
  const int wave = threadIdx.x >> 6;
  if ((threadIdx.x & 63) == 0) { ns->rs[wave] = s; ns->ri[wave] = i; }
  __syncthreads();
  if (threadIdx.x == 0) {
    float bs = ns->rs[0]; int bi = ns->ri[0];
#pragma unroll
    for (int w = 1; w < kNT / 64; ++w)
      if (ns->rs[w] > bs || (ns->rs[w] == bs && ns->ri[w] < bi)) { bs = ns->rs[w]; bi = ns->ri[w]; }
    ns->shS = bs; ns->shI = bi;
  }
  __syncthreads();
}

// Build 113x113 inclusive SAT (border row/col 0) in LDS, stride 116.
__device__ void build_sat(const float* __restrict__ xb, float* __restrict__ sat) {
  const int tid = threadIdx.x;
  for (int j = tid; j < kStride; j += kNT) sat[j] = 0.f;          // row 0 (+pad)
  for (int r = tid; r < 113; r += kNT) sat[r * kStride] = 0.f;    // col 0
  const float4* x4 = (const float4*)xb;                            // 12544%4==0, base aligned
  for (int i = tid; i < (kFeat * kFeat) / 4; i += kNT) {
    const float4 v = x4[i];
    const int r = i / (kFeat / 4);
    const int c = (i - r * (kFeat / 4)) * 4;
    float* dst = sat + (r + 1) * kStride + c + 1;
    dst[0] = v.x; dst[1] = v.y; dst[2] = v.z; dst[3] = v.w;
  }
  __syncthreads();
  // row inclusive scans: one wave per row, lanes = columns (conflict-free)
  const int wave = tid >> 6, lane = tid & 63;
  for (int r = 1 + wave; r <= kFeat; r += kNT / 64) {
    float* row = sat + r * kStride;
    float v = row[1 + lane];                       // cols 1..64
#pragma unroll
    for (int d = 1; d < 64; d <<= 1) { const float u = __shfl_up(v, d, 64); if (lane >= d) v += u; }
    row[1 + lane] = v;
    const float tot = __shfl(v, 63, 64);
    const int c = 65 + lane;                       // cols 65..112
    float w = (c <= kFeat) ? row[c] : 0.f;
#pragma unroll
    for (int d = 1; d < 64; d <<= 1) { const float u = __shfl_up(w, d, 64); if (lane >= d) w += u; }
    if (c <= kFeat) row[c] = w + tot;
  }
  __syncthreads();
  // column serial scans: lanes = columns, reads address-independent -> pipelined
  if (tid < kFeat) {
    const int col = tid + 1;
    float s = 0.f;
    for (int r = 1; r <= kFeat; ++r) { s += sat[r * kStride + col]; sat[r * kStride + col] = s; }
  }
  __syncthreads();
}

template<int RB, int RE>
__device__ __forceinline__ void pick_store(NmsShared* ns, int k, int slot,
                                           float* __restrict__ out_idx,
                                           float* __restrict__ out_sc, int b) {
  if (threadIdx.x == 0) {
    const int pi = ns->shI;
#pragma unroll
    for (int rr = RB; rr < RE; ++rr) {
      const int nr = kFeat - kRH[rr] + 1, nc = kFeat - kRW[rr] + 1;
      if (pi >= kOff[rr] && pi < kOff[rr] + nr * nc) {
        const int l = pi - kOff[rr];
        const int xi = l / nc, yi = l - xi * nc;
        const float x0u = xi * 4.0f - 1.0f, y0u = yi * 4.0f - 1.0f;
        const float x1 = x0u + kRH[rr] * 4.0f, y1 = y0u + kRW[rr] * 4.0f;
        const float x0 = fmaxf(x0u, 0.0f), y0 = fmaxf(y0u, 0.0f);
        ns->pX0[k] = x0; ns->pY0[k] = y0; ns->pX1[k] = x1; ns->pY1[k] = y1;
        ns->pA[k] = (x1 - x0 + 1.0f) * (y1 - y0 + 1.0f);
        ns->pI[k] = pi;
      }
    }
    out_idx[b * 7 + slot + k] = (float)pi;
    out_sc [b * 7 + slot + k] = ns->shS;
  }
  __syncthreads();
}

// Score this group's ratios (write wb, track argmax), then NP greedy-NMS picks.
template<int RB, int RE, int NP, int SLOT>
__device__ void run_group(const float* __restrict__ sat, NmsShared* ns,
                          float* __restrict__ wb,
                          float* __restrict__ out_idx, float* __restrict__ out_sc, int b) {
  const int tid = threadIdx.x;
  float best = -INFINITY; int bi = INT_MAX;

  // ---- scoring: quad-vectorized, aligned ds_read_b128 ----
#pragma unroll
  for (int rr = RB; rr < RE; ++rr) {
    const int rh = kRH[rr], rw = kRW[rr];
    const int nr = kFeat - rh + 1, nc = kFeat - rw + 1;
    const int nqy = (nc + 3) >> 2;
    const float inv = 1.0f / (float)(rh * rw);
    for (int q = tid; q < nr * nqy; q += kNT) {
      const int xi = q / nqy, qy = q - xi * nqy;     // nqy compile-time -> magic mul
      const int yi0 = qy << 2;
      const float* u = sat + xi * kStride;
      const float* d = u + rh * kStride;
      const float4 U0 = *(const float4*)(u + yi0);
      const float4 U1 = *(const float4*)(u + yi0 + rw);
      const float4 D0 = *(const float4*)(d + yi0);
      const float4 D1 = *(const float4*)(d + yi0 + rw);
      const float s0 = (D1.x - U1.x - D0.x + U0.x) * inv;
      const float s1 = (D1.y - U1.y - D0.y + U0.y) * inv;
      const float s2 = (D1.z - U1.z - D0.z + U0.z) * inv;
      const float s3 = (D1.w - U1.w - D0.w + U0.w) * inv;
      const int gi0 = kOff[rr] + xi * nc + yi0;
      float* w = wb + gi0;
      const int rem = nc - yi0;                      // >= 1
      w[0] = s0; if (s0 > best) { best = s0; bi = gi0; }
      if (rem > 1) { w[1] = s1; if (s1 > best) { best = s1; bi = gi0 + 1; } }
      if (rem > 2) { w[2] = s2; if (s2 > best) { best = s2; bi = gi0 + 2; } }
      if (rem > 3) { w[3] = s3; if (s3 > best) { best = s3; bi = gi0 + 3; } }
    }
  }

  // ---- pick 0 ----
  block_argmax(best, bi, ns);
  pick_store<RB, RE>(ns, 0, SLOT, out_idx, out_sc, b);

  // ---- picks 1..NP-1 ----
  for (int k = 1; k < NP; ++k) {
    float px0[NP], py0[NP], px1[NP], py1[NP], pa[NP]; int pix[NP];
#pragma unroll
    for (int p = 0; p < NP; ++p) {
      if (p < k) { px0[p] = ns->pX0[p]; py0[p] = ns->pY0[p]; px1[p] = ns->pX1[p];
                   py1[p] = ns->pY1[p]; pa[p] = ns->pA[p]; pix[p] = ns->pI[p]; }
    }
    best = -INFINITY; bi = INT_MAX;
#pragma unroll
    for (int rr = RB; rr < RE; ++rr) {
      const int rh = kRH[rr], rw = kRW[rr];
      const int nr = kFeat - rh + 1, nc = kFeat - rw + 1;
      const int nqy = (nc + 3) >> 2;
      const float inv = 1.0f / (float)(rh * rw);
      for (int q = tid; q < nr * nqy; q += kNT) {
        const int xi = q / nqy, qy = q - xi * nqy;
        const int yi0 = qy << 2;
        const float* u = sat + xi * kStride;
        const float* d = u + rh * kStride;
        const float4 U0 = *(const float4*)(u + yi0);
        const float4 U1 = *(const float4*)(u + yi0 + rw);
        const float4 D0 = *(const float4*)(d + yi0);
        const float4 D1 = *(const float4*)(d + yi0 + rw);
        float s4[4];
        s4[0] = (D1.x - U1.x - D0.x + U0.x) * inv;
        s4[1] = (D1.y - U1.y - D0.y + U0.y) * inv;
        s4[2] = (D1.z - U1.z - D0.z + U0.z) * inv;
        s4[3] = (D1.w - U1.w - D0.w + U0.w) * inv;
        const float X0u = xi * 4.0f - 1.0f;
        const float X1 = X0u + rh * 4.0f;
        const float X0 = fmaxf(X0u, 0.0f);
        const int gi0 = kOff[rr] + xi * nc + yi0;
        const int rem = nc - yi0;
#pragma unroll
        for (int j = 0; j < 4; ++j) {
          if (j >= rem) break;
          const int gi = gi0 + j;
          const float Y0u = (yi0 + j) * 4.0f - 1.0f;
          const float Y1 = Y0u + rw * 4.0f;
          const float Y0 = fmaxf(Y0u, 0.0f);
          const float A = (X1 - X0 + 1.0f) * (Y1 - Y0 + 1.0f);
          bool alive = true;
#pragma unroll
          for (int p = 0; p < NP; ++p) {
            if (p >= k) break;
            if (gi == pix[p]) { alive = false; break; }
            const float lx = fmaxf(X0, px0[p]), ly = fmaxf(Y0, py0[p]);
            const float rx = fminf(X1, px1[p]), ry = fminf(Y1, py1[p]);
            const float w = rx - lx + 1.0f, h = ry - ly + 1.0f;
            const float inter = (w < 0.0f || h < 0.0f) ? 0.0f : w * h;
            const float iou = inter / (A + pa[p] - inter);
            if (iou > 0.25f) { alive = false; break; }
          }
          if (alive && s4[j] > best) { best = s4[j]; bi = gi; }
        }
      }
    }
    block_argmax(best, bi, ns);
    pick_store<RB, RE>(ns, k, SLOT, out_idx, out_sc, b);
  }
}

__global__ __launch_bounds__(kNT, 6) void appm_fused(const float* __restrict__ x,
                                                     float* __restrict__ win,
                                                     float* __restrict__ out_idx,
                                                     float* __restrict__ out_sc) {
  __shared__ __align__(16) float sat[113 * kStride];   // 52,432 B
  __shared__ NmsShared ns;
  const int b = blockIdx.x / 3;
  const int t = blockIdx.x % 3;      // group id: each block handles one NMS group

  build_sat(x + (size_t)b * kFeat * kFeat, sat);

  float* wb = win + (size_t)b * kTotal;
  if (t == 0)       run_group<0, 3, 2, 0>(sat, &ns, wb, out_idx, out_sc, b);
  else if (t == 1)  run_group<3, 6, 3, 2>(sat, &ns, wb, out_idx, out_sc, b);
  else              run_group<6, 13, 2, 5>(sat, &ns, wb, out_idx, out_sc, b);
}

extern "C" void kernel_launch(void* const* d_in, const int* in_sizes, int n_in,
                              void* d_out, int out_size, void* d_ws, size_t ws_size,
                              hipStream_t stream) {
  const float* x = (const float*)d_in[0];
  float* out     = (float*)d_out;
  float* out_idx = out;                      // (256,7) indices as float values
  float* out_sc  = out + kBatch * 7;         // (256,7) picked scores
  float* win     = out + 2 * kBatch * 7;     // (256,96981) window scores

  appm_fused<<<kBatch * 3, kNT, 0, stream>>>(x, win, out_idx, out_sc);
}

// Round 4
// 165.866 us; speedup vs baseline: 2.1198x; 1.0902x over previous
//
#include <hip/hip_runtime.h>
#include <math.h>
#include <limits.h>

namespace {
constexpr int kFeat = 112;
constexpr int kBatch = 256;
constexpr int kTotal = 96981;
constexpr int kStride = 116;      // /4 -> float4-aligned columns (rw%4==0 for all ratios)
constexpr int kNT = 512;          // 8 waves; 3 blocks/CU (LDS-limited)
constexpr int kRH[13] = {16,12,20,24,20,28,32,24,40,28,40,28,36};
constexpr int kRW[13] = {16,20,12,24,28,20,32,40,24,40,28,36,28};
constexpr int kOff[13] = {0,9409,18802,28195,36116,44021,51926,58487,64984,71481,77686,83891,90436};
}

struct NmsShared {
  float rs[kNT / 64];
  int   ri[kNT / 64];
  float shS; int shI;
  float pX0[3], pY0[3], pX1[3], pY1[3], pA[3];
};

__device__ __forceinline__ void block_argmax(float s, int i, NmsShared* ns) {
  __syncthreads();                       // protect rs/ri reuse across passes
#pragma unroll
  for (int off = 32; off > 0; off >>= 1) {
    const float s2 = __shfl_down(s, off, 64);
    const int   i2 = __shfl_down(i, off, 64);
    if (s2 > s || (s2 == s && i2 < i)) { s = s2; i = i2; }
  }
  const int wave = threadIdx.x >> 6;
  if ((threadIdx.x & 63) == 0) { ns->rs[wave] = s; ns->ri[wave] = i; }
  __syncthreads();
  if (threadIdx.x == 0) {
    float bs = ns->rs[0]; int bi = ns->ri[0];
#pragma unroll
    for (int w = 1; w < kNT / 64; ++w)
      if (ns->rs[w] > bs || (ns->rs[w] == bs && ns->ri[w] < bi)) { bs = ns->rs[w]; bi = ns->ri[w]; }
    ns->shS = bs; ns->shI = bi;
  }
  __syncthreads();
}

// Build 113x113 inclusive SAT (border row/col 0) in LDS, stride 116.
__device__ void build_sat(const float* __restrict__ xb, float* __restrict__ sat) {
  const int tid = threadIdx.x;
  for (int j = tid; j < kStride; j += kNT) sat[j] = 0.f;          // row 0 (+pad)
  for (int r = tid; r < 113; r += kNT) sat[r * kStride] = 0.f;    // col 0
  const float4* x4 = (const float4*)xb;                            // 12544%4==0, base aligned
  for (int i = tid; i < (kFeat * kFeat) / 4; i += kNT) {
    const float4 v = x4[i];
    const int r = i / (kFeat / 4);
    const int c = (i - r * (kFeat / 4)) * 4;
    float* dst = sat + (r + 1) * kStride + c + 1;
    dst[0] = v.x; dst[1] = v.y; dst[2] = v.z; dst[3] = v.w;
  }
  __syncthreads();
  // row inclusive scans: one wave per row, lanes = columns (conflict-free)
  const int wave = tid >> 6, lane = tid & 63;
  for (int r = 1 + wave; r <= kFeat; r += kNT / 64) {
    float* row = sat + r * kStride;
    float v = row[1 + lane];                       // cols 1..64
#pragma unroll
    for (int d = 1; d < 64; d <<= 1) { const float u = __shfl_up(v, d, 64); if (lane >= d) v += u; }
    row[1 + lane] = v;
    const float tot = __shfl(v, 63, 64);
    const int c = 65 + lane;                       // cols 65..112
    float w = (c <= kFeat) ? row[c] : 0.f;
#pragma unroll
    for (int d = 1; d < 64; d <<= 1) { const float u = __shfl_up(w, d, 64); if (lane >= d) w += u; }
    if (c <= kFeat) row[c] = w + tot;
  }
  __syncthreads();
  // column scans, 4 segments of 28 rows: serial chain cut 112 -> 28
  const int seg = tid / kFeat;            // 0..3 for tid < 448
  const int col = tid - seg * kFeat + 1;  // 1..112
  if (tid < 4 * kFeat) {
    const int r0 = seg * 28 + 1;
    float s = 0.f;
    for (int r = r0; r < r0 + 28; ++r) { s += sat[r * kStride + col]; sat[r * kStride + col] = s; }
  }
  __syncthreads();
  float off = 0.f;
  if (tid < 4 * kFeat && seg > 0) {
#pragma unroll
    for (int s2 = 1; s2 <= 3; ++s2)
      if (s2 <= seg) off += sat[(28 * s2) * kStride + col];
  }
  __syncthreads();
  if (tid < 4 * kFeat && seg > 0) {
    const int r0 = seg * 28 + 1;
    for (int r = r0; r < r0 + 28; ++r) sat[r * kStride + col] += off;
  }
  __syncthreads();
}

template<int RB, int RE>
__device__ __forceinline__ void pick_store(NmsShared* ns, int k, int slot,
                                           float* __restrict__ out_idx,
                                           float* __restrict__ out_sc, int b) {
  if (threadIdx.x == 0) {
    const int pi = ns->shI;
#pragma unroll
    for (int rr = RB; rr < RE; ++rr) {
      const int nr = kFeat - kRH[rr] + 1, nc = kFeat - kRW[rr] + 1;
      if (pi >= kOff[rr] && pi < kOff[rr] + nr * nc) {
        const int l = pi - kOff[rr];
        const int xi = l / nc, yi = l - xi * nc;
        const float x0u = xi * 4.0f - 1.0f, y0u = yi * 4.0f - 1.0f;
        const float x1 = x0u + kRH[rr] * 4.0f, y1 = y0u + kRW[rr] * 4.0f;
        const float x0 = fmaxf(x0u, 0.0f), y0 = fmaxf(y0u, 0.0f);
        ns->pX0[k] = x0; ns->pY0[k] = y0; ns->pX1[k] = x1; ns->pY1[k] = y1;
        ns->pA[k] = (x1 - x0 + 1.0f) * (y1 - y0 + 1.0f);
      }
    }
    out_idx[b * 7 + slot + k] = (float)pi;
    out_sc [b * 7 + slot + k] = ns->shS;
  }
  __syncthreads();
}

// Score this group's ratios (write wb, track argmax), then NP greedy-NMS picks.
template<int RB, int RE, int NP, int SLOT>
__device__ void run_group(const float* __restrict__ sat, NmsShared* ns,
                          float* __restrict__ wb,
                          float* __restrict__ out_idx, float* __restrict__ out_sc, int b) {
  const int tid = threadIdx.x;
  float best = -INFINITY; int bi = INT_MAX;

  // ---- scoring: quad-vectorized, aligned ds_read_b128 ----
#pragma unroll
  for (int rr = RB; rr < RE; ++rr) {
    const int rh = kRH[rr], rw = kRW[rr];
    const int nr = kFeat - rh + 1, nc = kFeat - rw + 1;
    const int nqy = (nc + 3) >> 2;
    const float inv = 1.0f / (float)(rh * rw);
    for (int q = tid; q < nr * nqy; q += kNT) {
      const int xi = q / nqy, qy = q - xi * nqy;     // nqy compile-time -> magic mul
      const int yi0 = qy << 2;
      const float* u = sat + xi * kStride;
      const float* d = u + rh * kStride;
      const float4 U0 = *(const float4*)(u + yi0);
      const float4 U1 = *(const float4*)(u + yi0 + rw);
      const float4 D0 = *(const float4*)(d + yi0);
      const float4 D1 = *(const float4*)(d + yi0 + rw);
      const float s0 = (D1.x - U1.x - D0.x + U0.x) * inv;
      const float s1 = (D1.y - U1.y - D0.y + U0.y) * inv;
      const float s2 = (D1.z - U1.z - D0.z + U0.z) * inv;
      const float s3 = (D1.w - U1.w - D0.w + U0.w) * inv;
      const int gi0 = kOff[rr] + xi * nc + yi0;
      float* w = wb + gi0;
      const int rem = nc - yi0;                      // >= 1
      w[0] = s0; if (s0 > best) { best = s0; bi = gi0; }
      if (rem > 1) { w[1] = s1; if (s1 > best) { best = s1; bi = gi0 + 1; } }
      if (rem > 2) { w[2] = s2; if (s2 > best) { best = s2; bi = gi0 + 2; } }
      if (rem > 3) { w[3] = s3; if (s3 > best) { best = s3; bi = gi0 + 3; } }
    }
  }

  // ---- pick 0 ----
  block_argmax(best, bi, ns);
  pick_store<RB, RE>(ns, 0, SLOT, out_idx, out_sc, b);

  // ---- picks 1..NP-1: division-free separable suppression test ----
  // iou > 0.25  <=>  5*inter > A + pa   (all terms integer-valued floats -> exact;
  // nearest rational to 1/4 differs by >= 2^-19 >> div rounding -> verdict identical).
  // Self-window has inter == A == pa -> always suppressed (replaces idx removal).
  for (int k = 1; k < NP; ++k) {
    float px0[NP], py0[NP], px1[NP], py1[NP], pa[NP];
#pragma unroll
    for (int p = 0; p < NP; ++p) {
      if (p < k) { px0[p] = ns->pX0[p]; py0[p] = ns->pY0[p]; px1[p] = ns->pX1[p];
                   py1[p] = ns->pY1[p]; pa[p] = ns->pA[p]; }
    }
    best = -INFINITY; bi = INT_MAX;
#pragma unroll
    for (int rr = RB; rr < RE; ++rr) {
      const int rh = kRH[rr], rw = kRW[rr];
      const int nr = kFeat - rh + 1, nc = kFeat - rw + 1;
      const int nqy = (nc + 3) >> 2;
      const float inv = 1.0f / (float)(rh * rw);
      for (int q = tid; q < nr * nqy; q += kNT) {
        const int xi = q / nqy, qy = q - xi * nqy;
        const int yi0 = qy << 2;
        const float* u = sat + xi * kStride;
        const float* d = u + rh * kStride;
        const float4 U0 = *(const float4*)(u + yi0);
        const float4 U1 = *(const float4*)(u + yi0 + rw);
        const float4 D0 = *(const float4*)(d + yi0);
        const float4 D1 = *(const float4*)(d + yi0 + rw);
        float s4[4];
        s4[0] = (D1.x - U1.x - D0.x + U0.x) * inv;
        s4[1] = (D1.y - U1.y - D0.y + U0.y) * inv;
        s4[2] = (D1.z - U1.z - D0.z + U0.z) * inv;
        s4[3] = (D1.w - U1.w - D0.w + U0.w) * inv;
        // x-geometry: uniform over the quad (same xi)
        const float X0u = xi * 4.0f - 1.0f;
        const float X1 = X0u + rh * 4.0f;
        const float X0 = fmaxf(X0u, 0.0f);
        const float Ax = X1 - X0 + 1.0f;
        float wx[NP];
#pragma unroll
        for (int p = 0; p < NP; ++p)
          if (p < k) wx[p] = fminf(X1, px1[p]) - fmaxf(X0, px0[p]) + 1.0f;
        const int gi0 = kOff[rr] + xi * nc + yi0;
        const int rem = nc - yi0;
#pragma unroll
        for (int j = 0; j < 4; ++j) {
          if (j >= rem) break;
          const float Y0u = (yi0 + j) * 4.0f - 1.0f;
          const float Y1 = Y0u + rw * 4.0f;
          const float Y0 = fmaxf(Y0u, 0.0f);
          const float A = Ax * (Y1 - Y0 + 1.0f);
          bool alive = true;
#pragma unroll
          for (int p = 0; p < NP; ++p) {
            if (p >= k) break;
            const float hy = fminf(Y1, py1[p]) - fmaxf(Y0, py0[p]) + 1.0f;
            const bool sup = (wx[p] >= 0.0f) & (hy >= 0.0f) &
                             (5.0f * wx[p] * hy > A + pa[p]);
            alive &= !sup;
          }
          if (alive && s4[j] > best) { best = s4[j]; bi = gi0 + j; }
        }
      }
    }
    block_argmax(best, bi, ns);
    pick_store<RB, RE>(ns, k, SLOT, out_idx, out_sc, b);
  }
}

__global__ __launch_bounds__(kNT, 6) void appm_fused(const float* __restrict__ x,
                                                     float* __restrict__ win,
                                                     float* __restrict__ out_idx,
                                                     float* __restrict__ out_sc) {
  __shared__ __align__(16) float sat[113 * kStride];   // 52,432 B
  __shared__ NmsShared ns;
  const int b = blockIdx.x / 3;
  const int t = blockIdx.x % 3;      // group id: each block handles one NMS group

  build_sat(x + (size_t)b * kFeat * kFeat, sat);

  float* wb = win + (size_t)b * kTotal;
  if (t == 0)       run_group<0, 3, 2, 0>(sat, &ns, wb, out_idx, out_sc, b);
  else if (t == 1)  run_group<3, 6, 3, 2>(sat, &ns, wb, out_idx, out_sc, b);
  else              run_group<6, 13, 2, 5>(sat, &ns, wb, out_idx, out_sc, b);
}

extern "C" void kernel_launch(void* const* d_in, const int* in_sizes, int n_in,
                              void* d_out, int out_size, void* d_ws, size_t ws_size,
                              hipStream_t stream) {
  const float* x = (const float*)d_in[0];
  float* out     = (float*)d_out;
  float* out_idx = out;                      // (256,7) indices as float values
  float* out_sc  = out + kBatch * 7;         // (256,7) picked scores
  float* win     = out + 2 * kBatch * 7;     // (256,96981) window scores

  appm_fused<<<kBatch * 3, kNT, 0, stream>>>(x, win, out_idx, out_sc);
}